// Round 1
// baseline (228.345 us; speedup 1.0000x reference)
//
#include <hip/hip_runtime.h>

#define D_MODEL 512
#define P_DIM 64
#define C_DIM 32
#define B_DIM 32
#define N_PATCH 2048   // C_DIM * P_DIM
#define SELECT_N 256

typedef unsigned long long u64;

// ---------------------------------------------------------------------------
// K1: scores + per-chunk sort. One block per (b, chunk); chunk = 4 channels.
// NEW: 1024 threads/block (was 256) -- all 4 channels stream in parallel.
// 16 waves/CU instead of 4, and the 512 KB load phase has ZERO barriers
// (was 8: two per channel). Reduce + bitonic sort preserved verbatim; the
// sort runs in the first 4 waves (tid<256), barriers hoisted to block scope.
// Key = (monotone_bits<<32) | (2047 - local_n): descending u64 order ==
// score desc, ties -> lower idx (exact jax.lax.top_k semantics; keys unique).
// Bias unused: constant shift doesn't change selection; output is raw x.
// ---------------------------------------------------------------------------
__global__ __launch_bounds__(1024, 4) void score_sort_kernel(
    const float* __restrict__ x, const float* __restrict__ w,
    u64* __restrict__ chunks) {
  __shared__ float wl[D_MODEL];
  __shared__ float4 red[4][16][16];   // 16 KB: per-channel partials
  __shared__ float cs[256];           // the chunk's 256 scores
  __shared__ u64 skey[256];           // sort scratch

  const int blk   = blockIdx.x;   // b*8 + chunk
  const int b     = blk >> 3;
  const int chunk = blk & 7;
  const int tid   = threadIdx.x;  // 0..1023
  const int ch    = tid >> 8;     // channel within chunk, 0..3
  const int t     = tid & 255;
  const int pg    = t & 15;       // float4 group over p
  const int slice = t >> 4;       // 0..15

  if (tid < D_MODEL) wl[tid] = w[tid];
  __syncthreads();

  {
    const int bc = b * C_DIM + chunk * 4 + ch;
    const float* base = x + (size_t)bc * (D_MODEL * P_DIM) + pg * 4;
    float4 acc = make_float4(0.f, 0.f, 0.f, 0.f);
#pragma unroll 8
    for (int i = 0; i < 32; ++i) {
      const int d = slice + 16 * i;          // wave-contiguous 1 KB segments
      const float wd = wl[d];
      const float4 v = *(const float4*)(base + (size_t)d * P_DIM);
      acc.x += v.x * wd; acc.y += v.y * wd;
      acc.z += v.z * wd; acc.w += v.w * wd;
    }
    red[ch][slice][pg] = acc;
  }
  __syncthreads();
  if (t < 16) {
    float4 s = red[ch][0][t];
#pragma unroll
    for (int k = 1; k < 16; ++k) {
      const float4 t4 = red[ch][k][t];
      s.x += t4.x; s.y += t4.y; s.z += t4.z; s.w += t4.w;
    }
    cs[ch * 64 + t * 4 + 0] = s.x;   // p = t*4+q
    cs[ch * 64 + t * 4 + 1] = s.y;
    cs[ch * 64 + t * 4 + 2] = s.z;
    cs[ch * 64 + t * 4 + 3] = s.w;
  }
  __syncthreads();

  // Build key: local element tid = ch*64 + p; local_n = chunk*256 + tid.
  u64 e = 0;
  if (tid < 256) {
    unsigned u = __float_as_uint(cs[tid]);
    u ^= (u & 0x80000000u) ? 0xFFFFFFFFu : 0x80000000u;
    e = ((u64)u << 32) | (unsigned)(N_PATCH - 1 - (chunk * 256 + tid));
  }

  auto ce1 = [&](int j, int k) {           // in-wave CE, pair (tid, tid^j)
    const u64 p = __shfl_xor(e, j, 64);
    const bool keepmax = (((tid & j) == 0) == ((tid & k) == 0));
    e = keepmax ? (e > p ? e : p) : (e < p ? e : p);
  };
  auto ldsce = [&](int j, int k) {         // LDS CE, one thread per pair
    if ((tid & j) == 0) {
      const bool desc = ((tid & k) == 0);
      const u64 A = skey[tid], B = skey[tid | j];
      if (desc ? (B > A) : (B < A)) { skey[tid] = B; skey[tid | j] = A; }
    }
  };

  if (tid < 256) {
#pragma unroll
    for (int kk = 1; kk <= 6; ++kk) {      // stages k = 2..64: pure shfl
      const int k = 1 << kk;
      for (int j = k >> 1; j >= 1; j >>= 1) ce1(j, k);
    }
    skey[tid] = e;                         // stage k = 128 begins
  }
  __syncthreads();
  if (tid < 256) ldsce(64, 128);
  __syncthreads();
  if (tid < 256) {
    e = skey[tid];
    for (int j = 32; j >= 1; j >>= 1) ce1(j, 128);
    skey[tid] = e;                         // stage k = 256 begins
  }
  __syncthreads();
  if (tid < 256) ldsce(128, 256);
  __syncthreads();
  if (tid < 256) ldsce(64, 256);
  __syncthreads();
  if (tid < 256) {
    e = skey[tid];
    for (int j = 32; j >= 1; j >>= 1) ce1(j, 256);
    chunks[(size_t)b * N_PATCH + chunk * 256 + tid] = e;  // sorted desc
  }
}

// ---------------------------------------------------------------------------
// K2a: per-batch merge-prune, ONCE per batch (was redundantly re-done by all
// 32 channel blocks). One block per b. Loads the 8 sorted chunks (16 KB),
// reduces to the sorted top-256 via bitonic merge-prune: top-L of two desc
// L-lists = elementwise max(A[i], B[L-1-i]), which is bitonic -> log2(L) CE
// phases re-sort it. 3 rounds: 8->4->2->1. Writes final patch ids (rank ->
// n), 1 KB per batch.
// ---------------------------------------------------------------------------
__global__ __launch_bounds__(256) void merge_kernel(
    const u64* __restrict__ chunks, int* __restrict__ fin) {
  __shared__ u64 key[N_PATCH];   // 16 KB
  const int b = blockIdx.x;
  const int t = threadIdx.x;

#pragma unroll
  for (int l = 0; l < 8; ++l)
    key[l * 256 + t] = chunks[(size_t)b * N_PATCH + l * 256 + t];
  __syncthreads();

  // ---- Round 1: 8 desc lists -> 4 (max-step staged in regs, then merge) --
  {
    u64 r[4];
#pragma unroll
    for (int m = 0; m < 4; ++m) {
      const u64 A = key[(2 * m) * 256 + t];
      const u64 B = key[(2 * m + 1) * 256 + (255 - t)];
      r[m] = A > B ? A : B;
    }
    __syncthreads();
#pragma unroll
    for (int m = 0; m < 4; ++m) key[m * 256 + t] = r[m];
    __syncthreads();
    for (int j = 128; j >= 1; j >>= 1) {   // desc bitonic merge, 4 lists
#pragma unroll
      for (int q = 0; q < 2; ++q) {
        const int pidx = t + q * 256;      // 512 pairs
        const int m  = pidx >> 7;
        const int rk = pidx & 127;
        const int i  = ((rk & ~(j - 1)) << 1) | (rk & (j - 1));
        const int i0 = m * 256 + i;
        const u64 A = key[i0], B = key[i0 + j];
        if (B > A) { key[i0] = B; key[i0 + j] = A; }
      }
      __syncthreads();
    }
  }
  // ---- Round 2: 4 -> 2 ---------------------------------------------------
  {
    u64 r[2];
#pragma unroll
    for (int m = 0; m < 2; ++m) {
      const u64 A = key[(2 * m) * 256 + t];
      const u64 B = key[(2 * m + 1) * 256 + (255 - t)];
      r[m] = A > B ? A : B;
    }
    __syncthreads();
#pragma unroll
    for (int m = 0; m < 2; ++m) key[m * 256 + t] = r[m];
    __syncthreads();
    for (int j = 128; j >= 1; j >>= 1) {   // 256 pairs, 1/thread
      const int m  = t >> 7;
      const int rk = t & 127;
      const int i  = ((rk & ~(j - 1)) << 1) | (rk & (j - 1));
      const int i0 = m * 256 + i;
      const u64 A = key[i0], B = key[i0 + j];
      if (B > A) { key[i0] = B; key[i0 + j] = A; }
      __syncthreads();
    }
  }
  // ---- Round 3: 2 -> 1 (final top-256, desc) -----------------------------
  {
    const u64 A = key[t];
    const u64 B = key[256 + (255 - t)];
    const u64 r = A > B ? A : B;
    __syncthreads();
    key[t] = r;
    __syncthreads();
    for (int j = 128; j >= 1; j >>= 1) {   // 128 pairs
      if (t < 128) {
        const int i  = ((t & ~(j - 1)) << 1) | (t & (j - 1));
        const u64 A2 = key[i], B2 = key[i + j];
        if (B2 > A2) { key[i] = B2; key[i + j] = A2; }
      }
      __syncthreads();
    }
  }

  // rank t -> global patch id n
  fin[b * SELECT_N + t] = N_PATCH - 1 - (int)(key[t] & 0xFFFFFFFFu);
}

// ---------------------------------------------------------------------------
// K2b: pure gather. One block per (b,c). Reads the batch's final 256 patch
// ids (1 KB, L2-hot), filters its channel (avg ~8 hits), streams its 128 KB
// x-tile through padded LDS, writes selected patches coalesced over d. The
// first tile prefetch is issued at kernel entry so its latency overlaps the
// list read + filter. No merge, no key LDS -> ~24 fewer syncthreads/block.
// ---------------------------------------------------------------------------
__global__ __launch_bounds__(256, 4) void gather_kernel(
    const float* __restrict__ x, const int* __restrict__ fin,
    float* __restrict__ out) {
  __shared__ float tile[64][65];   // 16,640 B, bank-conflict-free columns
  __shared__ int plist[64];
  __shared__ int ilist[64];
  __shared__ int s_m;
  const int bc = blockIdx.x;   // b*32 + c
  const int b  = bc >> 5;
  const int c  = bc & 31;
  const int t  = threadIdx.x;  // 256

  const int p4 = (t & 15) * 4;
  const int r0 = t >> 4;
  const int jr = t >> 6;
  const int dd = t & 63;
  const float* xb = x + (size_t)bc * (D_MODEL * P_DIM);

  // Issue chunk-0 tile loads NOW: latency overlaps list read + filter.
  float4 pre[4];
#pragma unroll
  for (int q = 0; q < 4; ++q)
    pre[q] = *(const float4*)(xb + (size_t)(r0 + q * 16) * P_DIM + p4);

  if (t == 0) s_m = 0;
  __syncthreads();
  {
    const int n = fin[b * SELECT_N + t];
    if ((n >> 6) == c) {
      const int slot = atomicAdd(&s_m, 1);
      plist[slot] = n & 63;
      ilist[slot] = t;     // output rank
    }
  }
  __syncthreads();
  const int m = s_m;
  if (m == 0) return;

  // ---- Gather: stream 128 KB tile through padded LDS, coalesced writes ---
  for (int d0 = 0; d0 < D_MODEL; d0 += 64) {
    __syncthreads();   // tile region free (prev chunk's readers done)
#pragma unroll
    for (int q = 0; q < 4; ++q) {
      const int drow = r0 + q * 16;
      tile[drow][p4]     = pre[q].x;
      tile[drow][p4 + 1] = pre[q].y;
      tile[drow][p4 + 2] = pre[q].z;
      tile[drow][p4 + 3] = pre[q].w;
    }
    __syncthreads();
    if (d0 + 64 < D_MODEL) {    // prefetch next chunk; overlaps out-writes
#pragma unroll
      for (int q = 0; q < 4; ++q)
        pre[q] = *(const float4*)(xb + (size_t)(d0 + 64 + r0 + q * 16) * P_DIM + p4);
    }
    for (int j = jr; j < m; j += 4)
      out[(size_t)(b * SELECT_N + ilist[j]) * D_MODEL + d0 + dd] =
          tile[dd][plist[j]];
  }
}

extern "C" void kernel_launch(void* const* d_in, const int* in_sizes, int n_in,
                              void* d_out, int out_size, void* d_ws, size_t ws_size,
                              hipStream_t stream) {
  const float* x = (const float*)d_in[0];
  const float* w = (const float*)d_in[1];
  // d_in[2] (bias) intentionally unused: constant shift doesn't change top-k.

  u64* chunks = (u64*)d_ws;                                   // 512 KB
  int* fin    = (int*)((char*)d_ws + (size_t)B_DIM * N_PATCH * sizeof(u64)); // 32 KB
  float* out  = (float*)d_out;

  score_sort_kernel<<<B_DIM * 8, 1024, 0, stream>>>(x, w, chunks);
  merge_kernel<<<B_DIM, 256, 0, stream>>>(chunks, fin);
  gather_kernel<<<B_DIM * C_DIM, 256, 0, stream>>>(x, fin, out);
}

// Round 2
// 228.055 us; speedup vs baseline: 1.0013x; 1.0013x over previous
//
#include <hip/hip_runtime.h>

#define D_MODEL 512
#define P_DIM 64
#define C_DIM 32
#define B_DIM 32
#define N_PATCH 2048   // C_DIM * P_DIM
#define SELECT_N 256

typedef unsigned long long u64;

// ---------------------------------------------------------------------------
// K1: scores + per-chunk sort. One block per (b, chunk); chunk = 4 channels.
// 1024 threads/block: all 4 channels stream in parallel, zero barriers in
// the 512 KB load phase. Reduce + bitonic sort in waves 0-3 (tid<256).
// Key = (monotone_bits<<32) | (2047 - local_n): descending u64 order ==
// score desc, ties -> lower idx (exact jax.lax.top_k semantics; keys unique).
// Bias unused: constant shift doesn't change selection; output is raw x.
// ---------------------------------------------------------------------------
__global__ __launch_bounds__(1024, 4) void score_sort_kernel(
    const float* __restrict__ x, const float* __restrict__ w,
    u64* __restrict__ chunks) {
  __shared__ float wl[D_MODEL];
  __shared__ float4 red[4][16][16];   // 16 KB: per-channel partials
  __shared__ float cs[256];           // the chunk's 256 scores
  __shared__ u64 skey[256];           // sort scratch

  const int blk   = blockIdx.x;   // b*8 + chunk
  const int b     = blk >> 3;
  const int chunk = blk & 7;
  const int tid   = threadIdx.x;  // 0..1023
  const int ch    = tid >> 8;     // channel within chunk, 0..3
  const int t     = tid & 255;
  const int pg    = t & 15;       // float4 group over p
  const int slice = t >> 4;       // 0..15

  if (tid < D_MODEL) wl[tid] = w[tid];
  __syncthreads();

  {
    const int bc = b * C_DIM + chunk * 4 + ch;
    const float* base = x + (size_t)bc * (D_MODEL * P_DIM) + pg * 4;
    float4 acc = make_float4(0.f, 0.f, 0.f, 0.f);
#pragma unroll 8
    for (int i = 0; i < 32; ++i) {
      const int d = slice + 16 * i;          // wave-contiguous 1 KB segments
      const float wd = wl[d];
      const float4 v = *(const float4*)(base + (size_t)d * P_DIM);
      acc.x += v.x * wd; acc.y += v.y * wd;
      acc.z += v.z * wd; acc.w += v.w * wd;
    }
    red[ch][slice][pg] = acc;
  }
  __syncthreads();
  if (t < 16) {
    float4 s = red[ch][0][t];
#pragma unroll
    for (int k = 1; k < 16; ++k) {
      const float4 t4 = red[ch][k][t];
      s.x += t4.x; s.y += t4.y; s.z += t4.z; s.w += t4.w;
    }
    cs[ch * 64 + t * 4 + 0] = s.x;   // p = t*4+q
    cs[ch * 64 + t * 4 + 1] = s.y;
    cs[ch * 64 + t * 4 + 2] = s.z;
    cs[ch * 64 + t * 4 + 3] = s.w;
  }
  __syncthreads();

  // Build key: local element tid = ch*64 + p; local_n = chunk*256 + tid.
  u64 e = 0;
  if (tid < 256) {
    unsigned u = __float_as_uint(cs[tid]);
    u ^= (u & 0x80000000u) ? 0xFFFFFFFFu : 0x80000000u;
    e = ((u64)u << 32) | (unsigned)(N_PATCH - 1 - (chunk * 256 + tid));
  }

  auto ce1 = [&](int j, int k) {           // in-wave CE, pair (tid, tid^j)
    const u64 p = __shfl_xor(e, j, 64);
    const bool keepmax = (((tid & j) == 0) == ((tid & k) == 0));
    e = keepmax ? (e > p ? e : p) : (e < p ? e : p);
  };
  auto ldsce = [&](int j, int k) {         // LDS CE, one thread per pair
    if ((tid & j) == 0) {
      const bool desc = ((tid & k) == 0);
      const u64 A = skey[tid], B = skey[tid | j];
      if (desc ? (B > A) : (B < A)) { skey[tid] = B; skey[tid | j] = A; }
    }
  };

  if (tid < 256) {
#pragma unroll
    for (int kk = 1; kk <= 6; ++kk) {      // stages k = 2..64: pure shfl
      const int k = 1 << kk;
      for (int j = k >> 1; j >= 1; j >>= 1) ce1(j, k);
    }
    skey[tid] = e;                         // stage k = 128 begins
  }
  __syncthreads();
  if (tid < 256) ldsce(64, 128);
  __syncthreads();
  if (tid < 256) {
    e = skey[tid];
    for (int j = 32; j >= 1; j >>= 1) ce1(j, 128);
    skey[tid] = e;                         // stage k = 256 begins
  }
  __syncthreads();
  if (tid < 256) ldsce(128, 256);
  __syncthreads();
  if (tid < 256) ldsce(64, 256);
  __syncthreads();
  if (tid < 256) {
    e = skey[tid];
    for (int j = 32; j >= 1; j >>= 1) ce1(j, 256);
    chunks[(size_t)b * N_PATCH + chunk * 256 + tid] = e;  // sorted desc
  }
}

// ---------------------------------------------------------------------------
// K2a: per-batch merge-prune, NOW wave-register bitonic (was ~30 LDS/barrier
// phases; now 3 barriers total). One block (256 thr = 4 waves) per batch.
// A 256-key desc merge of two desc lists lives in ONE wave: 4 keys/lane,
// element i = lane*4 + q. Max-step: r[i] = max(A[i], B[255-i]) (top-256 of
// the pair, bitonic). Re-sort desc = 8 CE phases: j=128..4 are shfl_xor with
// lane mask j>>2 (32..1); j=2,1 are in-register. Tree 8->4->2->1 uses
// 4 -> 2 -> 1 waves with LDS handoff between rounds. Same network + key
// semantics as the proven LDS version. Writes final patch ids (rank -> n).
// ---------------------------------------------------------------------------
__global__ __launch_bounds__(256) void merge_kernel(
    const u64* __restrict__ chunks, int* __restrict__ fin) {
  __shared__ u64 lds[1024];      // 8 KB handoff
  const int b    = blockIdx.x;
  const int t    = threadIdx.x;  // 256
  const int wave = t >> 6;       // 0..3
  const int lane = t & 63;

  const u64* cb = chunks + (size_t)b * N_PATCH;

  u64 e[4];   // element i = lane*4 + q, list of 256 desc keys per wave

  // desc bitonic merge of a bitonic 256-seq held in one wave's registers
  auto mergephases = [&]() {
#pragma unroll
    for (int ph = 0; ph < 6; ++ph) {
      const int lm = 32 >> ph;             // lane xor mask: 32,16,8,4,2,1
      const bool hi = (lane & lm) == 0;    // (i & j)==0, j = lm<<2
#pragma unroll
      for (int q = 0; q < 4; ++q) {
        const u64 p = __shfl_xor(e[q], lm, 64);
        e[q] = hi ? (e[q] > p ? e[q] : p) : (e[q] < p ? e[q] : p);
      }
    }
    // j = 2: pairs (q0,q2),(q1,q3); max at lower q
    { const u64 a = e[0], c = e[2]; e[0] = a > c ? a : c; e[2] = a > c ? c : a; }
    { const u64 a = e[1], c = e[3]; e[1] = a > c ? a : c; e[3] = a > c ? c : a; }
    // j = 1: pairs (q0,q1),(q2,q3)
    { const u64 a = e[0], c = e[1]; e[0] = a > c ? a : c; e[1] = a > c ? c : a; }
    { const u64 a = e[2], c = e[3]; e[2] = a > c ? a : c; e[3] = a > c ? c : a; }
  };

  // ---- Round 1: 8 -> 4. Wave w merges chunk lists 2w, 2w+1 (from global).
  {
    const u64* A = cb + (2 * wave) * 256;
    const u64* B = cb + (2 * wave + 1) * 256;
#pragma unroll
    for (int q = 0; q < 4; ++q) {
      const int i = lane * 4 + q;
      const u64 a  = A[i];
      const u64 bv = B[255 - i];
      e[q] = a > bv ? a : bv;
    }
    mergephases();
#pragma unroll
    for (int q = 0; q < 4; ++q) lds[wave * 256 + lane * 4 + q] = e[q];
  }
  __syncthreads();

  // ---- Round 2: 4 -> 2. Waves 0,1 merge LDS lists 2w, 2w+1.
  if (wave < 2) {
    const u64* A = lds + (2 * wave) * 256;
    const u64* B = lds + (2 * wave + 1) * 256;
#pragma unroll
    for (int q = 0; q < 4; ++q) {
      const int i = lane * 4 + q;
      const u64 a  = A[i];
      const u64 bv = B[255 - i];
      e[q] = a > bv ? a : bv;
    }
  }
  __syncthreads();               // all R2 reads done before overwrites
  if (wave < 2) {
    mergephases();
#pragma unroll
    for (int q = 0; q < 4; ++q) lds[wave * 256 + lane * 4 + q] = e[q];
  }
  __syncthreads();

  // ---- Round 3: 2 -> 1. Wave 0 merges LDS lists 0,1; writes fin.
  if (wave == 0) {
#pragma unroll
    for (int q = 0; q < 4; ++q) {
      const int i = lane * 4 + q;
      const u64 a  = lds[i];
      const u64 bv = lds[256 + 255 - i];
      e[q] = a > bv ? a : bv;
    }
    mergephases();
    int4 r;                      // rank i -> global patch id n
    r.x = N_PATCH - 1 - (int)(e[0] & 0xFFFFFFFFu);
    r.y = N_PATCH - 1 - (int)(e[1] & 0xFFFFFFFFu);
    r.z = N_PATCH - 1 - (int)(e[2] & 0xFFFFFFFFu);
    r.w = N_PATCH - 1 - (int)(e[3] & 0xFFFFFFFFu);
    *(int4*)(fin + b * SELECT_N + lane * 4) = r;
  }
}

// ---------------------------------------------------------------------------
// K2b: pure gather. One block per (b,c). Reads the batch's final 256 patch
// ids (1 KB, L2-hot), filters its channel (avg ~8 hits), streams its 128 KB
// x-tile through padded LDS, writes selected patches coalesced over d. The
// first tile prefetch is issued at kernel entry so its latency overlaps the
// list read + filter.
// ---------------------------------------------------------------------------
__global__ __launch_bounds__(256, 4) void gather_kernel(
    const float* __restrict__ x, const int* __restrict__ fin,
    float* __restrict__ out) {
  __shared__ float tile[64][65];   // 16,640 B, bank-conflict-free columns
  __shared__ int plist[64];
  __shared__ int ilist[64];
  __shared__ int s_m;
  const int bc = blockIdx.x;   // b*32 + c
  const int b  = bc >> 5;
  const int c  = bc & 31;
  const int t  = threadIdx.x;  // 256

  const int p4 = (t & 15) * 4;
  const int r0 = t >> 4;
  const int jr = t >> 6;
  const int dd = t & 63;
  const float* xb = x + (size_t)bc * (D_MODEL * P_DIM);

  // Issue chunk-0 tile loads NOW: latency overlaps list read + filter.
  float4 pre[4];
#pragma unroll
  for (int q = 0; q < 4; ++q)
    pre[q] = *(const float4*)(xb + (size_t)(r0 + q * 16) * P_DIM + p4);

  if (t == 0) s_m = 0;
  __syncthreads();
  {
    const int n = fin[b * SELECT_N + t];
    if ((n >> 6) == c) {
      const int slot = atomicAdd(&s_m, 1);
      plist[slot] = n & 63;
      ilist[slot] = t;     // output rank
    }
  }
  __syncthreads();
  const int m = s_m;
  if (m == 0) return;

  // ---- Gather: stream 128 KB tile through padded LDS, coalesced writes ---
  for (int d0 = 0; d0 < D_MODEL; d0 += 64) {
    __syncthreads();   // tile region free (prev chunk's readers done)
#pragma unroll
    for (int q = 0; q < 4; ++q) {
      const int drow = r0 + q * 16;
      tile[drow][p4]     = pre[q].x;
      tile[drow][p4 + 1] = pre[q].y;
      tile[drow][p4 + 2] = pre[q].z;
      tile[drow][p4 + 3] = pre[q].w;
    }
    __syncthreads();
    if (d0 + 64 < D_MODEL) {    // prefetch next chunk; overlaps out-writes
#pragma unroll
      for (int q = 0; q < 4; ++q)
        pre[q] = *(const float4*)(xb + (size_t)(d0 + 64 + r0 + q * 16) * P_DIM + p4);
    }
    for (int j = jr; j < m; j += 4)
      out[(size_t)(b * SELECT_N + ilist[j]) * D_MODEL + d0 + dd] =
          tile[dd][plist[j]];
  }
}

extern "C" void kernel_launch(void* const* d_in, const int* in_sizes, int n_in,
                              void* d_out, int out_size, void* d_ws, size_t ws_size,
                              hipStream_t stream) {
  const float* x = (const float*)d_in[0];
  const float* w = (const float*)d_in[1];
  // d_in[2] (bias) intentionally unused: constant shift doesn't change top-k.

  u64* chunks = (u64*)d_ws;                                   // 512 KB
  int* fin    = (int*)((char*)d_ws + (size_t)B_DIM * N_PATCH * sizeof(u64)); // 32 KB
  float* out  = (float*)d_out;

  score_sort_kernel<<<B_DIM * 8, 1024, 0, stream>>>(x, w, chunks);
  merge_kernel<<<B_DIM, 256, 0, stream>>>(chunks, fin);
  gather_kernel<<<B_DIM * C_DIM, 256, 0, stream>>>(x, fin, out);
}

// Round 3
// 226.834 us; speedup vs baseline: 1.0067x; 1.0054x over previous
//
#include <hip/hip_runtime.h>

#define D_MODEL 512
#define P_DIM 64
#define C_DIM 32
#define B_DIM 32
#define N_PATCH 2048   // C_DIM * P_DIM
#define SELECT_N 256

typedef unsigned long long u64;

// ---------------------------------------------------------------------------
// K1: scores + per-chunk sort. One block per (b, chunk); chunk = 4 channels.
// 1024 threads/block: all 4 channels stream in parallel, zero barriers in
// the 512 KB load phase. Reduce + bitonic sort in waves 0-3 (tid<256).
// Key = (monotone_bits<<32) | (2047 - local_n): descending u64 order ==
// score desc, ties -> lower idx (exact jax.lax.top_k semantics; keys unique).
// Bias unused: constant shift doesn't change selection; output is raw x.
// ---------------------------------------------------------------------------
__global__ __launch_bounds__(1024, 4) void score_sort_kernel(
    const float* __restrict__ x, const float* __restrict__ w,
    u64* __restrict__ chunks) {
  __shared__ float wl[D_MODEL];
  __shared__ float4 red[4][16][16];   // 16 KB: per-channel partials
  __shared__ float cs[256];           // the chunk's 256 scores
  __shared__ u64 skey[256];           // sort scratch

  const int blk   = blockIdx.x;   // b*8 + chunk
  const int b     = blk >> 3;
  const int chunk = blk & 7;
  const int tid   = threadIdx.x;  // 0..1023
  const int ch    = tid >> 8;     // channel within chunk, 0..3
  const int t     = tid & 255;
  const int pg    = t & 15;       // float4 group over p
  const int slice = t >> 4;       // 0..15

  if (tid < D_MODEL) wl[tid] = w[tid];
  __syncthreads();

  {
    const int bc = b * C_DIM + chunk * 4 + ch;
    const float* base = x + (size_t)bc * (D_MODEL * P_DIM) + pg * 4;
    float4 acc = make_float4(0.f, 0.f, 0.f, 0.f);
#pragma unroll 8
    for (int i = 0; i < 32; ++i) {
      const int d = slice + 16 * i;          // wave-contiguous 1 KB segments
      const float wd = wl[d];
      const float4 v = *(const float4*)(base + (size_t)d * P_DIM);
      acc.x += v.x * wd; acc.y += v.y * wd;
      acc.z += v.z * wd; acc.w += v.w * wd;
    }
    red[ch][slice][pg] = acc;
  }
  __syncthreads();
  if (t < 16) {
    float4 s = red[ch][0][t];
#pragma unroll
    for (int k = 1; k < 16; ++k) {
      const float4 t4 = red[ch][k][t];
      s.x += t4.x; s.y += t4.y; s.z += t4.z; s.w += t4.w;
    }
    cs[ch * 64 + t * 4 + 0] = s.x;   // p = t*4+q
    cs[ch * 64 + t * 4 + 1] = s.y;
    cs[ch * 64 + t * 4 + 2] = s.z;
    cs[ch * 64 + t * 4 + 3] = s.w;
  }
  __syncthreads();

  // Build key: local element tid = ch*64 + p; local_n = chunk*256 + tid.
  u64 e = 0;
  if (tid < 256) {
    unsigned u = __float_as_uint(cs[tid]);
    u ^= (u & 0x80000000u) ? 0xFFFFFFFFu : 0x80000000u;
    e = ((u64)u << 32) | (unsigned)(N_PATCH - 1 - (chunk * 256 + tid));
  }

  auto ce1 = [&](int j, int k) {           // in-wave CE, pair (tid, tid^j)
    const u64 p = __shfl_xor(e, j, 64);
    const bool keepmax = (((tid & j) == 0) == ((tid & k) == 0));
    e = keepmax ? (e > p ? e : p) : (e < p ? e : p);
  };
  auto ldsce = [&](int j, int k) {         // LDS CE, one thread per pair
    if ((tid & j) == 0) {
      const bool desc = ((tid & k) == 0);
      const u64 A = skey[tid], B = skey[tid | j];
      if (desc ? (B > A) : (B < A)) { skey[tid] = B; skey[tid | j] = A; }
    }
  };

  if (tid < 256) {
#pragma unroll
    for (int kk = 1; kk <= 6; ++kk) {      // stages k = 2..64: pure shfl
      const int k = 1 << kk;
      for (int j = k >> 1; j >= 1; j >>= 1) ce1(j, k);
    }
    skey[tid] = e;                         // stage k = 128 begins
  }
  __syncthreads();
  if (tid < 256) ldsce(64, 128);
  __syncthreads();
  if (tid < 256) {
    e = skey[tid];
    for (int j = 32; j >= 1; j >>= 1) ce1(j, 128);
    skey[tid] = e;                         // stage k = 256 begins
  }
  __syncthreads();
  if (tid < 256) ldsce(128, 256);
  __syncthreads();
  if (tid < 256) ldsce(64, 256);
  __syncthreads();
  if (tid < 256) {
    e = skey[tid];
    for (int j = 32; j >= 1; j >>= 1) ce1(j, 256);
    chunks[(size_t)b * N_PATCH + chunk * 256 + tid] = e;  // sorted desc
  }
}

// ---------------------------------------------------------------------------
// K2: merge + gather, 2-kernel structure (best-measured, R0) with the
// R2-verified wave-register merge embedded per block (redundant x32, ~1 us
// of pure shfl work, overlapped with the entry-issued tile prefetch; the
// 16 KB chunk load is L2/L3-hot). One block (256 thr = 4 waves) per (b,c).
// Merge: 256-key desc merge of two desc lists in ONE wave, 4 keys/lane,
// element i = lane*4 + q. Max-step r[i] = max(A[i], B[255-i]) -> bitonic;
// re-sort desc = 6 shfl_xor phases (j=128..4 -> lane mask 32..1) + 2
// in-register phases (j=2,1). Tree 8->4->2->1 over waves 4->2->1 with LDS
// handoff. Then wave 0 filters this block's channel (avg ~8 hits), and the
// block streams its 128 KB x-tile through padded LDS, writing selected
// patches coalesced over d.
// ---------------------------------------------------------------------------
struct GatherSmem {
  float tile[64][65];   // 16,640 B
  int plist[64];        // bytes 16,640..16,896
  int ilist[64];        // bytes 16,896..17,152
};
union __align__(16) K2Smem {
  u64 mrg[1024];        // 8,192 B merge handoff (dead before tile is written)
  GatherSmem g;         // 17,152 B  (plist/ilist live beyond mrg[1024])
};

__global__ __launch_bounds__(256, 4) void merge_gather_kernel(
    const float* __restrict__ x, const u64* __restrict__ chunks,
    float* __restrict__ out) {
  __shared__ K2Smem sm;
  __shared__ int s_m;
  const int bc   = blockIdx.x;   // b*32 + c
  const int b    = bc >> 5;
  const int c    = bc & 31;
  const int t    = threadIdx.x;  // 256
  const int wave = t >> 6;       // 0..3
  const int lane = t & 63;

  const int p4 = (t & 15) * 4;
  const int r0 = t >> 4;
  const int jr = t >> 6;
  const int dd = t & 63;
  const float* xb = x + (size_t)bc * (D_MODEL * P_DIM);
  const u64*   cb = chunks + (size_t)b * N_PATCH;

  // Issue chunk-0 tile loads NOW: latency/BW overlaps the whole merge.
  float4 pre[4];
#pragma unroll
  for (int q = 0; q < 4; ++q)
    pre[q] = *(const float4*)(xb + (size_t)(r0 + q * 16) * P_DIM + p4);

  if (t == 0) s_m = 0;

  u64 e[4];   // element i = lane*4 + q, list of 256 desc keys per wave

  // desc bitonic merge of a bitonic 256-seq held in one wave's registers
  auto mergephases = [&]() {
#pragma unroll
    for (int ph = 0; ph < 6; ++ph) {
      const int lm = 32 >> ph;             // lane xor mask: 32,16,8,4,2,1
      const bool hi = (lane & lm) == 0;    // (i & j)==0, j = lm<<2
#pragma unroll
      for (int q = 0; q < 4; ++q) {
        const u64 p = __shfl_xor(e[q], lm, 64);
        e[q] = hi ? (e[q] > p ? e[q] : p) : (e[q] < p ? e[q] : p);
      }
    }
    // j = 2: pairs (q0,q2),(q1,q3); max at lower q
    { const u64 a = e[0], cc = e[2]; e[0] = a > cc ? a : cc; e[2] = a > cc ? cc : a; }
    { const u64 a = e[1], cc = e[3]; e[1] = a > cc ? a : cc; e[3] = a > cc ? cc : a; }
    // j = 1: pairs (q0,q1),(q2,q3)
    { const u64 a = e[0], cc = e[1]; e[0] = a > cc ? a : cc; e[1] = a > cc ? cc : a; }
    { const u64 a = e[2], cc = e[3]; e[2] = a > cc ? a : cc; e[3] = a > cc ? cc : a; }
  };

  // ---- Round 1: 8 -> 4. Wave w merges chunk lists 2w, 2w+1 (L2-hot). ----
  {
    const u64* A = cb + (2 * wave) * 256;
    const u64* B = cb + (2 * wave + 1) * 256;
#pragma unroll
    for (int q = 0; q < 4; ++q) {
      const int i = lane * 4 + q;
      const u64 a  = A[i];
      const u64 bv = B[255 - i];
      e[q] = a > bv ? a : bv;
    }
    mergephases();
#pragma unroll
    for (int q = 0; q < 4; ++q) sm.mrg[wave * 256 + lane * 4 + q] = e[q];
  }
  __syncthreads();

  // ---- Round 2: 4 -> 2. Waves 0,1 merge LDS lists 2w, 2w+1. -------------
  if (wave < 2) {
    const u64* A = sm.mrg + (2 * wave) * 256;
    const u64* B = sm.mrg + (2 * wave + 1) * 256;
#pragma unroll
    for (int q = 0; q < 4; ++q) {
      const int i = lane * 4 + q;
      const u64 a  = A[i];
      const u64 bv = B[255 - i];
      e[q] = a > bv ? a : bv;
    }
  }
  __syncthreads();               // all R2 reads done before overwrites
  if (wave < 2) {
    mergephases();
#pragma unroll
    for (int q = 0; q < 4; ++q) sm.mrg[wave * 256 + lane * 4 + q] = e[q];
  }
  __syncthreads();

  // ---- Round 3: 2 -> 1. Wave 0 merges, filters channel c. ---------------
  // plist/ilist live at bytes 16,640+ -- no overlap with mrg[1024] (8 KB).
  if (wave == 0) {
#pragma unroll
    for (int q = 0; q < 4; ++q) {
      const int i = lane * 4 + q;
      const u64 a  = sm.mrg[i];
      const u64 bv = sm.mrg[256 + 255 - i];
      e[q] = a > bv ? a : bv;
    }
    mergephases();
#pragma unroll
    for (int q = 0; q < 4; ++q) {
      const int rank = lane * 4 + q;           // output rank
      const int n = N_PATCH - 1 - (int)(e[q] & 0xFFFFFFFFu);
      if ((n >> 6) == c) {
        const int slot = atomicAdd(&s_m, 1);
        sm.g.plist[slot] = n & 63;
        sm.g.ilist[slot] = rank;
      }
    }
  }
  __syncthreads();
  const int m = s_m;
  if (m == 0) return;

  // ---- Gather: stream 128 KB tile through padded LDS, coalesced writes ---
  for (int d0 = 0; d0 < D_MODEL; d0 += 64) {
    __syncthreads();   // tile region free (merge done / prev chunk done)
#pragma unroll
    for (int q = 0; q < 4; ++q) {
      const int drow = r0 + q * 16;
      sm.g.tile[drow][p4]     = pre[q].x;
      sm.g.tile[drow][p4 + 1] = pre[q].y;
      sm.g.tile[drow][p4 + 2] = pre[q].z;
      sm.g.tile[drow][p4 + 3] = pre[q].w;
    }
    __syncthreads();
    if (d0 + 64 < D_MODEL) {    // prefetch next chunk; overlaps out-writes
#pragma unroll
      for (int q = 0; q < 4; ++q)
        pre[q] = *(const float4*)(xb + (size_t)(d0 + 64 + r0 + q * 16) * P_DIM + p4);
    }
    for (int j = jr; j < m; j += 4)
      out[(size_t)(b * SELECT_N + sm.g.ilist[j]) * D_MODEL + d0 + dd] =
          sm.g.tile[dd][sm.g.plist[j]];
  }
}

extern "C" void kernel_launch(void* const* d_in, const int* in_sizes, int n_in,
                              void* d_out, int out_size, void* d_ws, size_t ws_size,
                              hipStream_t stream) {
  const float* x = (const float*)d_in[0];
  const float* w = (const float*)d_in[1];
  // d_in[2] (bias) intentionally unused: constant shift doesn't change top-k.

  u64*   chunks = (u64*)d_ws;        // 32 batches x 2048 keys x 8 B = 512 KB
  float* out    = (float*)d_out;

  score_sort_kernel<<<B_DIM * 8, 1024, 0, stream>>>(x, w, chunks);
  merge_gather_kernel<<<B_DIM * C_DIM, 256, 0, stream>>>(x, chunks, out);
}